// Round 12
// baseline (2797.790 us; speedup 1.0000x reference)
//
#include <hip/hip_runtime.h>
#include <math.h>

typedef short bf16x8 __attribute__((ext_vector_type(8)));
typedef float f32x4 __attribute__((ext_vector_type(4)));
typedef unsigned short u16;
typedef unsigned int u32;

// float-region offsets in ws
#define WSUMS 0
#define TOTWS 1
#define WSUM_OFF 2
#define TOTW_OFF 8194
#define WB_BYTE 98432      // start of u16 region (byte offset)

// u16-region offsets
#define GWI_U 0            // [384][32]   gru Wih (cols 0..29, pad 0)
#define GWH_U 12288        // [384][128]  gru Whh
#define EO_U  61440        // [7][512][256]  enc (Wih|Whh)
#define DO_U  978944       // [512][320]  dec packed
#define RING_U 1142784     // [8192][12][128] activations t=12..23 (bf16)
#define RING_BYTES 25165824

__constant__ int cLAG[8] = {144,120,96,72,48,24,0,168};

__device__ __forceinline__ float sig_(float x){ return 1.0f/(1.0f+__expf(-x)); }
__device__ __forceinline__ float th_(float x){ float e=__expf(2.0f*x); return 1.0f - 2.0f/(e+1.0f); }
__device__ __forceinline__ u16 f2b(float x){ u32 u=__float_as_uint(x); return (u16)((u + 0x7fffu + ((u>>16)&1u))>>16); }
__device__ __forceinline__ float b2f(u16 v){ return __uint_as_float(((u32)v)<<16); }

#define MFMA(a,b,c) __builtin_amdgcn_mfma_f32_16x16x32_bf16(a,b,c,0,0,0)

__global__ void scale_kernel(const float* __restrict__ tgt,
                             const float* __restrict__ obs,
                             float* __restrict__ ws)
{
  __shared__ float s1[256], s2[256];
  int b = blockIdx.x*256 + threadIdx.x;
  float wsum=0.f, totw=0.f;
  const float* tr = tgt + b*336 + 168;
  const float* wr = obs + b*336 + 168;
  for(int t=0;t<168;t++){ float w=wr[t]; wsum += fabsf(tr[t])*w; totw += w; }
  ws[WSUM_OFF + b] = wsum;
  ws[TOTW_OFF + b] = totw;
  s1[threadIdx.x]=wsum; s2[threadIdx.x]=totw;
  __syncthreads();
  for(int s=128;s>0;s>>=1){
    if(threadIdx.x<s){ s1[threadIdx.x]+=s1[threadIdx.x+s]; s2[threadIdx.x]+=s2[threadIdx.x+s]; }
    __syncthreads();
  }
  if(threadIdx.x==0){ atomicAdd(&ws[WSUMS], s1[0]); atomicAdd(&ws[TOTWS], s2[0]); }
}

__global__ void prep_w(const float* __restrict__ gWih, const float* __restrict__ gWhh,
                       const float* __restrict__ eWih, const float* __restrict__ eWhh,
                       const float* __restrict__ dWih, const float* __restrict__ dWhh,
                       float* __restrict__ ws)
{
  u16* WU = (u16*)((char*)ws + WB_BYTE);
  int tid = blockIdx.x*blockDim.x + threadIdx.x;
  int nt = gridDim.x*blockDim.x;
  for(int i=tid;i<12288;i+=nt){ int n=i>>5,k=i&31; WU[GWI_U+i]=(k<30)?f2b(gWih[n*30+k]):(u16)0; }
  for(int i=tid;i<49152;i+=nt){ int n=i>>7,k=i&127; WU[GWH_U+i]=f2b(gWhh[n*128+k]); }
  for(int i=tid;i<917504;i+=nt){
    int s=i>>17,r2=i&131071,n=r2>>8,k=r2&255;
    float v=(k<128)?eWih[(s*512+n)*128+k]:eWhh[(s*512+n)*128+(k-128)];
    WU[EO_U+i]=f2b(v);
  }
  for(int i=tid;i<163840;i+=nt){
    int n=i/320, k=i-n*320; float v;
    if(k<128)       v=dWih[n*180+30+k];
    else if(k<136)  v=dWih[n*180+(k-128)];
    else if(k<140)  v=dWih[n*180+8+(k-136)];
    else if(k<144)  v=dWih[n*180+158+(k-140)];
    else if(k<162)  v=dWih[n*180+12+(k-144)];
    else if(k<180)  v=dWih[n*180+162+(k-162)];
    else if(k<192)  v=0.f;
    else            v=dWhh[n*128+(k-192)];
    WU[DO_U+i]=f2b(v);
  }
}

// M=32 rows/block, 256 blocks, ONE grid pass. Activations: t<12 in LDS encbuf
// (rows beta12(r,t)=(t>>2)*128+r*4+(t&3)), t>=12 in global RING (per-XCD slice
// 3.1 MB -> L2-resident; r10's full ring was 6.3 MB and thrashed HBM).
// Weight loads: r9-style compiler-scheduled (pins/opaque all measured worse).
__global__ __launch_bounds__(512,1)
void deepar_main(const int* __restrict__ cat, const float* __restrict__ sreal,
                 const float* __restrict__ tgt, const float* __restrict__ ptf,
                 const float* __restrict__ ftf, const float* __restrict__ emb,
                 const float* __restrict__ gbih, const float* __restrict__ gbhh,
                 const float* __restrict__ encb, const float* __restrict__ decb,
                 const float* __restrict__ outW, const float* __restrict__ outb,
                 float* __restrict__ ws, float* __restrict__ out)
{
  const u16* __restrict__ WU=(const u16*)((const char*)ws+WB_BYTE);
  u16* __restrict__ RING=(u16*)((char*)ws+WB_BYTE) + RING_U;

  __shared__ __align__(16) u16 encbuf[384*136];   // 12t x 32r (beta12 rows) 104 KB
  __shared__ __align__(16) u16 Ast[2][32*136];    // A-tile dbuf / GRU ring-half h-tile
  __shared__ __align__(16) u16 hstash[2][32*136]; // recurrent h, dbuf
  __shared__ __align__(16) u16 Xast[64*40];       // GRU x feats (statics prebuilt)
  __shared__ __align__(16) u16 Xdast[32*72];      // dec extra feats (statics prebuilt)
  __shared__ u16 statb[32][18];
  __shared__ float scl_s[32], invs_s[32];
  __shared__ float outw_s[128];
  __shared__ float red[32][8];
  __shared__ float outb_s;

  const int tid=threadIdx.x;
  const int b0=blockIdx.x*32;
  const int wv=tid>>6, lane=tid&63, quad=lane>>4, l15=lane&15;

  if(tid<32){
    int b=b0+tid;
    float wsumv=ws[WSUM_OFF+b], totw=ws[TOTW_OFF+b];
    float def=ws[WSUMS]/fmaxf(ws[TOTWS],1.f);
    float sc=fmaxf(1e-10f,(wsumv>0.f)?wsumv/fmaxf(totw,1.f):def);
    scl_s[tid]=sc; invs_s[tid]=1.f/sc;
  }
  if(tid<128) outw_s[tid]=outW[tid];
  if(tid==128) outb_s=outb[0];
  { int r=tid>>4, k=tid&15; statb[r][k]=f2b(emb[cat[b0+r]*16+k]); }
  { const uint4 z4={0,0,0,0};
    for(int i=tid;i<6528;i+=512) *(uint4*)(encbuf+i*8)=z4;         // 384*136 u16
    for(int i=tid;i<1088;i+=512) *(uint4*)(&hstash[0][0]+i*8)=z4;  // 2*32*136 u16
  }
  __syncthreads();
  if(tid<32){ statb[tid][16]=f2b(sreal[b0+tid]); statb[tid][17]=f2b(logf(scl_s[tid])); }
  __syncthreads();
  for(int i=tid;i<1280;i+=512){ int a=i/20, k=i-a*20+12;       // GRU statics (r=a>>1)
    Xast[a*40+k]=(k<30)?statb[a>>1][k-12]:(u16)0; }
  for(int i=tid;i<1536;i+=512){ int rr=i/48, k=i-rr*48+16;     // dec statics
    u16 v; if(k<34) v=statb[rr][k-16]; else if(k<52) v=statb[rr][k-34]; else v=0;
    Xdast[rr*72+k]=v; }
  __syncthreads();

  int loI[3], loH[3], loE[4], loD[4];
  #pragma unroll
  for(int j=0;j<3;j++){ int nb=(wv+j*8)*16+l15; loI[j]=nb*32+quad*8; loH[j]=nb*128+quad*8; }
  #pragma unroll
  for(int j=0;j<4;j++){ int nb=(wv+j*8)*16+l15; loE[j]=nb*256+quad*8; loD[j]=nb*320+quad*8; }

  float gbi[3], gbh[3];
  #pragma unroll
  for(int j=0;j<3;j++){ int nb=(wv+j*8)*16+l15; gbi[j]=gbih[nb]; gbh[j]=gbhh[nb]; }
  float bd[4];
  #pragma unroll
  for(int j=0;j<4;j++) bd[j]=decb[(wv+j*8)*16+l15];

  const int hc=wv*16+l15;
  float cst[2][4];
  #pragma unroll
  for(int m=0;m<2;m++){ cst[m][0]=0.f; cst[m][1]=0.f; cst[m][2]=0.f; cst[m][3]=0.f; }
  int p=0;

  for(int seg=0;seg<7;seg++){
    // ======== GRU: 12 chunks x (32r x 2t) = 64 A-rows ========
    for(int c=0;c<12;c++){
      const int t0=2*c, G=t0>>2;
      // stage dynamic x cols [0,12)
      for(int i=tid;i<768;i+=512){ int a=i/12, kk=i-a*12;
        int r=a>>1, t=t0+(a&1);
        u16 v=(kk<8)? f2b(tgt[(b0+r)*336+seg*24+t+cLAG[kk]]*invs_s[r])
                    : f2b(ptf[((size_t)((b0+r)*336+168+seg*24+t))*4+(kk-8)]);
        Xast[a*40+kk]=v; }
      if(c>=6){ // stage prev enc_out (ring half) into Ast[0], row a=r*2+tloc
        #pragma unroll
        for(int q=0;q<2;q++){ int i=tid*2+q; int a=i>>4, c8=(i&15)*8;
          *(uint4*)(&Ast[0][a*136+c8]) =
            *(const uint4*)(RING + ((size_t)((b0+(a>>1))*12 + t0-12+(a&1)))*128 + c8); }
      }
      __syncthreads();

      const u16* hbase=(c<6)? encbuf : &Ast[0][0];
      int hoff[4];                       // frag-row offset per mt (a = mt*16+l15)
      #pragma unroll
      for(int mt=0;mt<4;mt++){
        int a=mt*16+l15;
        hoff[mt]=(c<6)? (G*128 + (a>>1)*4 + ((t0+(a&1))&3))*136 : a*136;
      }
      f32x4 ai[3][4], ah[3][4];
      #pragma unroll
      for(int j=0;j<3;j++)
        #pragma unroll
        for(int mt=0;mt<4;mt++){
          ai[j][mt]=(f32x4){gbi[j],gbi[j],gbi[j],gbi[j]};
          ah[j][mt]=(f32x4){gbh[j],gbh[j],gbh[j],gbh[j]};
        }
      #pragma unroll
      for(int mt=0;mt<4;mt++){
        bf16x8 af=*(const bf16x8*)(Xast+(mt*16+l15)*40+quad*8);
        #pragma unroll
        for(int j=0;j<3;j++){
          bf16x8 wI=*(const bf16x8*)(WU+GWI_U+loI[j]);
          ai[j][mt]=MFMA(af,wI,ai[j][mt]);
        }
      }
      #pragma unroll
      for(int kt=0;kt<4;kt++)
        #pragma unroll
        for(int mt=0;mt<4;mt++){
          bf16x8 af=*(const bf16x8*)(hbase+hoff[mt]+kt*32+quad*8);
          #pragma unroll
          for(int j=0;j<3;j++){
            bf16x8 wH=*(const bf16x8*)(WU+GWH_U+loH[j]+kt*32);
            ah[j][mt]=MFMA(af,wH,ah[j][mt]);
          }
        }
      u16 hv16[4][4];
      #pragma unroll
      for(int mt=0;mt<4;mt++)
        #pragma unroll
        for(int reg=0;reg<4;reg++){
          int rr=mt*8+quad*2+(reg>>1), tl=reg&1;        // a=mt*16+quad*4+reg
          int co=(c<6)? (G*128 + rr*4 + ((t0+tl)&3))*136 + hc
                      : (mt*16+quad*4+reg)*136 + hc;
          float hp=b2f(hbase[co]);
          float rg=sig_(ai[0][mt][reg]+ah[0][mt][reg]);
          float zg=sig_(ai[1][mt][reg]+ah[1][mt][reg]);
          float nn=th_(ai[2][mt][reg]+rg*ah[2][mt][reg]);
          hv16[mt][reg]=f2b((1.f-zg)*nn+zg*hp);
        }
      __syncthreads();   // all reads done before overwrite
      #pragma unroll
      for(int mt=0;mt<4;mt++)
        #pragma unroll
        for(int reg=0;reg<4;reg++){
          int rr=mt*8+quad*2+(reg>>1), tl=reg&1;
          if(c<6) encbuf[(G*128 + rr*4 + ((t0+tl)&3))*136 + hc]=hv16[mt][reg];
          else    RING[((size_t)((b0+rr)*12 + t0-12+tl))*128 + hc]=hv16[mt][reg];
        }
    }
    __syncthreads();     // hv complete before enc staging

    // ======== encoder LSTM: 24 steps, weights compiler-streamed from L2 ========
    float be[4];
    #pragma unroll
    for(int j=0;j<4;j++) be[j]=encb[seg*512+(wv+j*8)*16+l15];
    const u16* __restrict__ wbase = WU + EO_U + (size_t)seg*131072;

    for(int t=0;t<24;t++){
      u16* Ab=&Ast[t&1][0];
      { int row=tid>>4, q=tid&15;
        const u16* src=(t<12)? encbuf + ((size_t)((t>>2)*128+row*4+(t&3)))*136 + q*8
                             : RING + ((size_t)((b0+row)*12+(t-12)))*128 + q*8;
        *(uint4*)(Ab+row*136+q*8)=*(const uint4*)src; }
      __syncthreads();
      const u16* Hb=&hstash[p][0];
      f32x4 acc[4][2];
      #pragma unroll
      for(int j=0;j<4;j++){ acc[j][0]=(f32x4){be[j],be[j],be[j],be[j]}; acc[j][1]=acc[j][0]; }
      #pragma unroll
      for(int kt=0;kt<8;kt++){
        bf16x8 a0=(kt<4)? *(const bf16x8*)(Ab+l15*136+kt*32+quad*8)
                        : *(const bf16x8*)(Hb+l15*136+(kt-4)*32+quad*8);
        bf16x8 a1=(kt<4)? *(const bf16x8*)(Ab+(16+l15)*136+kt*32+quad*8)
                        : *(const bf16x8*)(Hb+(16+l15)*136+(kt-4)*32+quad*8);
        #pragma unroll
        for(int j=0;j<4;j++){
          bf16x8 b=*(const bf16x8*)(wbase+loE[j]+kt*32);
          acc[j][0]=MFMA(a0,b,acc[j][0]);
          acc[j][1]=MFMA(a1,b,acc[j][1]);
        }
      }
      int pn=p^1;
      #pragma unroll
      for(int mt=0;mt<2;mt++)
        #pragma unroll
        for(int r=0;r<4;r++){
          float ig=sig_(acc[0][mt][r]), fg=sig_(acc[1][mt][r]);
          float gg=th_(acc[2][mt][r]),  og=sig_(acc[3][mt][r]);
          float c_=fg*cst[mt][r]+ig*gg; cst[mt][r]=c_;
          u16 hb16=f2b(og*th_(c_));
          int row=mt*16+quad*4+r;
          hstash[pn][row*136+hc]=hb16;
          if(t<12) encbuf[((size_t)((t>>2)*128+row*4+(t&3)))*136+hc]=hb16;
          else     RING[((size_t)((b0+row)*12+(t-12)))*128+hc]=hb16;
        }
      p=pn;
    }
    __syncthreads();
  }

  // ======== decoder LSTM + projection ========
  for(int t=0;t<24;t++){
    u16* Ab=&Ast[t&1][0];
    { int row=tid>>4, q=tid&15;
      const u16* src=(t<12)? encbuf + ((size_t)((t>>2)*128+row*4+(t&3)))*136 + q*8
                           : RING + ((size_t)((b0+row)*12+(t-12)))*128 + q*8;
      *(uint4*)(Ab+row*136+q*8)=*(const uint4*)src; }
    if(tid<32){
      int rr=tid; float iv=invs_s[rr];
      __align__(16) u16 rowv[16];
      #pragma unroll
      for(int j=0;j<8;j++) rowv[j]=f2b(tgt[(b0+rr)*336 + cLAG[j] + t]*iv);
      #pragma unroll
      for(int j=0;j<4;j++) rowv[8+j]=f2b(ptf[((size_t)((b0+rr)*336+168+t))*4 + j]);
      #pragma unroll
      for(int j=0;j<4;j++) rowv[12+j]=f2b(ftf[(b0+rr)*96 + t*4 + j]);
      *(uint4*)(Xdast+rr*72)  =*(const uint4*)rowv;
      *(uint4*)(Xdast+rr*72+8)=*(const uint4*)(rowv+8);
    }
    __syncthreads();                                   // B1
    const u16* Hb=&hstash[p][0];
    f32x4 acc[4][2];
    #pragma unroll
    for(int j=0;j<4;j++){ acc[j][0]=(f32x4){bd[j],bd[j],bd[j],bd[j]}; acc[j][1]=acc[j][0]; }
    #pragma unroll
    for(int kt=0;kt<10;kt++){
      bf16x8 a0=(kt<4)? *(const bf16x8*)(Ab+l15*136+kt*32+quad*8)
              :(kt<6)? *(const bf16x8*)(Xdast+l15*72+(kt-4)*32+quad*8)
                     : *(const bf16x8*)(Hb+l15*136+(kt-6)*32+quad*8);
      bf16x8 a1=(kt<4)? *(const bf16x8*)(Ab+(16+l15)*136+kt*32+quad*8)
              :(kt<6)? *(const bf16x8*)(Xdast+(16+l15)*72+(kt-4)*32+quad*8)
                     : *(const bf16x8*)(Hb+(16+l15)*136+(kt-6)*32+quad*8);
      #pragma unroll
      for(int j=0;j<4;j++){
        bf16x8 b=*(const bf16x8*)(WU+DO_U+loD[j]+kt*32);
        acc[j][0]=MFMA(a0,b,acc[j][0]);
        acc[j][1]=MFMA(a1,b,acc[j][1]);
      }
    }
    int pn=p^1;
    #pragma unroll
    for(int mt=0;mt<2;mt++)
      #pragma unroll
      for(int r=0;r<4;r++){
        float ig=sig_(acc[0][mt][r]), fg=sig_(acc[1][mt][r]);
        float gg=th_(acc[2][mt][r]),  og=sig_(acc[3][mt][r]);
        float c_=fg*cst[mt][r]+ig*gg; cst[mt][r]=c_;
        hstash[pn][(mt*16+quad*4+r)*136+hc]=f2b(og*th_(c_));
      }
    __syncthreads();                                   // B2: h complete
    if(tid<256){ int row=tid>>3,g=tid&7; float s=0.f;
      #pragma unroll
      for(int i=0;i<16;i++) s+=b2f(hstash[pn][row*136+g*16+i])*outw_s[g*16+i];
      red[row][g]=s; }
    __syncthreads();                                   // B3
    if(tid<32){ float s=outb_s;
      #pragma unroll
      for(int g=0;g<8;g++) s+=red[tid][g];
      out[(b0+tid)*24+t]=s*scl_s[tid]; }
    p=pn;
  }
}

extern "C" void kernel_launch(void* const* d_in, const int* in_sizes, int n_in,
                              void* d_out, int out_size, void* d_ws, size_t ws_size,
                              hipStream_t stream)
{
  (void)in_sizes; (void)n_in; (void)out_size; (void)ws_size;
  const int*   cat  = (const int*)d_in[0];
  const float* sreal= (const float*)d_in[1];
  const float* ptf  = (const float*)d_in[2];
  const float* tgt  = (const float*)d_in[3];
  const float* obs  = (const float*)d_in[4];
  const float* ftf  = (const float*)d_in[5];
  const float* emb  = (const float*)d_in[6];
  const float* gWih = (const float*)d_in[7];
  const float* gWhh = (const float*)d_in[8];
  const float* gbih = (const float*)d_in[9];
  const float* gbhh = (const float*)d_in[10];
  const float* eWih = (const float*)d_in[11];
  const float* eWhh = (const float*)d_in[12];
  const float* encb = (const float*)d_in[13];
  const float* dWih = (const float*)d_in[14];
  const float* dWhh = (const float*)d_in[15];
  const float* decb = (const float*)d_in[16];
  const float* outW = (const float*)d_in[17];
  const float* outb = (const float*)d_in[18];
  float* ws  = (float*)d_ws;
  float* out = (float*)d_out;

  hipMemsetAsync(d_ws, 0, 2*sizeof(float), stream);
  hipMemsetAsync((char*)d_ws + WB_BYTE + (size_t)RING_U*2, 0, RING_BYTES, stream);
  scale_kernel<<<dim3(8192/256), dim3(256), 0, stream>>>(tgt, obs, ws);
  prep_w<<<dim3(512), dim3(256), 0, stream>>>(gWih,gWhh,eWih,eWhh,dWih,dWhh,ws);
  deepar_main<<<dim3(256), dim3(512), 0, stream>>>(cat,sreal,tgt,ptf,ftf,emb,
                                                   gbih,gbhh,encb,decb,outW,outb,ws,out);
}